// Round 1
// baseline (2976.820 us; speedup 1.0000x reference)
//
#include <hip/hip_runtime.h>
#include <math.h>

// Problem constants
#define NN 2048
#define DD 128
#define KK 16
#define TT 16
#define EE 8192
#define TWOE 16384
#define CNT 262144.0f   // T * 2E

__device__ __forceinline__ float sigmoidf_(float x) { return 1.f / (1.f + expf(-x)); }
__device__ __forceinline__ float softplusf_(float x) { return fmaxf(x, 0.f) + log1pf(expf(-fabsf(x))); }

// ---------------------------------------------------------------------------
// Init: build concatenated weight matrices
//  Bg  [768x128]: rows 0..383 = Wih[:, :128]+Wih[:,128:], rows 384..767 = Whh
//  Bms [256x128]: rows 0..127 = W_mean, rows 128..255 = W_std
// ---------------------------------------------------------------------------
__launch_bounds__(256)
__global__ void prep_kernel(const float* __restrict__ Wih_n, const float* __restrict__ Whh_n,
                            const float* __restrict__ Wih_c, const float* __restrict__ Whh_c,
                            const float* __restrict__ W_pmean, const float* __restrict__ W_pstd,
                            const float* __restrict__ W_bmean, const float* __restrict__ W_bstd,
                            float* __restrict__ Bg_n, float* __restrict__ Bg_c,
                            float* __restrict__ Bms_n, float* __restrict__ Bms_c)
{
    int idx = blockIdx.x * 256 + threadIdx.x;   // < 262144
    if (idx < 98304) {
        int r = idx;
        if (r < 49152) { int j = r >> 7, k2 = r & 127; Bg_n[r] = Wih_n[j*256 + k2] + Wih_n[j*256 + 128 + k2]; }
        else Bg_n[r] = Whh_n[r - 49152];
    } else if (idx < 196608) {
        int r = idx - 98304;
        if (r < 49152) { int j = r >> 7, k2 = r & 127; Bg_c[r] = Wih_c[j*256 + k2] + Wih_c[j*256 + 128 + k2]; }
        else Bg_c[r] = Whh_c[r - 49152];
    } else if (idx < 229376) {
        int r = idx - 196608;
        Bms_n[r] = (r < 16384) ? W_pmean[r] : W_pstd[r - 16384];
    } else {
        int r = idx - 229376;
        Bms_c[r] = (r < 16384) ? W_bmean[r] : W_bstd[r - 16384];
    }
}

// ---------------------------------------------------------------------------
// alpha: a_m, kld_alpha
// ---------------------------------------------------------------------------
__launch_bounds__(128)
__global__ void alpha_kernel(const float* __restrict__ amE, const float* __restrict__ asE,
                             const int* __restrict__ sidx, float* __restrict__ a_m, float* __restrict__ acc)
{
    __shared__ float red[128];
    int d = threadIdx.x;
    int s = sidx[0];
    float am = amE[s*128 + d];
    float as = softplusf_(asE[s*128 + d]);
    a_m[d] = am;
    float e = -logf(as) + 0.5f*(as*as + am*am) - 0.5f;
    red[d] = e; __syncthreads();
    for (int st = 64; st > 0; st >>= 1) { if (d < st) red[d] += red[d + st]; __syncthreads(); }
    if (d == 0) acc[2] = red[0];
}

// ---------------------------------------------------------------------------
// phi0/beta0 GEMV: out[row] = dot(a_m, W[row,:]) + b[row]   (264192 rows)
// one wave per row, lane-split k, butterfly reduce
// ---------------------------------------------------------------------------
__launch_bounds__(256)
__global__ void phi0_kernel(const float* __restrict__ Wp, const float* __restrict__ bp,
                            const float* __restrict__ Wb, const float* __restrict__ bb,
                            const float* __restrict__ a_m, float* __restrict__ phi0, float* __restrict__ beta0)
{
    int wid = threadIdx.x >> 6, l = threadIdx.x & 63;
    long long row = (long long)blockIdx.x * 4 + wid;     // < 264192
    const float* W; const float* b; float* o; long long r = row;
    if (row < 262144) { W = Wp; b = bp; o = phi0; }
    else { W = Wb; b = bb; o = beta0; r = row - 262144; }
    const float* wr = W + r * 128;
    float acc = a_m[l] * wr[l] + a_m[64 + l] * wr[64 + l];
    #pragma unroll
    for (int m = 32; m >= 1; m >>= 1) acc += __shfl_xor(acc, m);
    if (l == 0) o[r] = acc + b[r];
}

// ---------------------------------------------------------------------------
// Generic tiled SGEMM: C = A @ B^T + bias, A selected per N-range (cols <
// Nsplit use A1, >= Nsplit use A2), one extra M-tile (blockIdx.y==MtPhi) for
// the 16-row beta problem. Tiles 64x64, K=128 in chunks of 32, 4x4 microtile.
// ---------------------------------------------------------------------------
__launch_bounds__(256)
__global__ void gemm_bias(const float* __restrict__ Ap1, const float* __restrict__ Ap2,
                          const float* __restrict__ Ab1, const float* __restrict__ Ab2,
                          const float* __restrict__ Bphi, const float* __restrict__ Bbeta,
                          const float* __restrict__ b0p, const float* __restrict__ b1p,
                          const float* __restrict__ b0b, const float* __restrict__ b1b,
                          float* __restrict__ Cphi, float* __restrict__ Cbeta,
                          int Ncols, int Nsplit, int MtPhi, int Mbeta)
{
    __shared__ float As[32][68];
    __shared__ float Bs[32][68];
    bool isBeta = (blockIdx.y == (unsigned)MtPhi);
    int n0 = blockIdx.x * 64;
    const float* A = isBeta ? ((n0 >= Nsplit) ? Ab2 : Ab1) : ((n0 >= Nsplit) ? Ap2 : Ap1);
    const float* B = isBeta ? Bbeta : Bphi;
    const float* b0 = isBeta ? b0b : b0p;
    const float* b1 = isBeta ? b1b : b1p;
    float* C = isBeta ? Cbeta : Cphi;
    int M = isBeta ? Mbeta : MtPhi * 64;
    int m0 = isBeta ? 0 : blockIdx.y * 64;
    int tid = threadIdx.x;
    int tx = tid & 15, ty = tid >> 4;
    float accu[4][4] = {};
    int lr = tid >> 2;          // 0..63
    int lk = (tid & 3) * 8;     // 0,8,16,24
    for (int k0 = 0; k0 < 128; k0 += 32) {
        int arow = m0 + lr;
        const float* ap = A + (size_t)arow * 128 + k0 + lk;
        const float* bp = B + (size_t)(n0 + lr) * 128 + k0 + lk;
        #pragma unroll
        for (int qq = 0; qq < 8; ++qq) {
            As[lk + qq][lr] = (arow < M) ? ap[qq] : 0.f;
            Bs[lk + qq][lr] = bp[qq];
        }
        __syncthreads();
        #pragma unroll
        for (int kk = 0; kk < 32; ++kk) {
            float av[4], bv[4];
            #pragma unroll
            for (int i2 = 0; i2 < 4; ++i2) av[i2] = As[kk][ty*4 + i2];
            #pragma unroll
            for (int j2 = 0; j2 < 4; ++j2) bv[j2] = Bs[kk][tx*4 + j2];
            #pragma unroll
            for (int i2 = 0; i2 < 4; ++i2)
                #pragma unroll
                for (int j2 = 0; j2 < 4; ++j2)
                    accu[i2][j2] = fmaf(av[i2], bv[j2], accu[i2][j2]);
        }
        __syncthreads();
    }
    #pragma unroll
    for (int i2 = 0; i2 < 4; ++i2) {
        int row = m0 + ty*4 + i2;
        if (row >= M) continue;
        #pragma unroll
        for (int j2 = 0; j2 < 4; ++j2) {
            int col = n0 + tx*4 + j2;
            float bv = (col < Nsplit) ? b0[col] : b1[col - Nsplit];
            C[(size_t)row * Ncols + col] = accu[i2][j2] + bv;
        }
    }
}

// ---------------------------------------------------------------------------
// GRU gate elementwise: G row layout [gi_r gi_z gi_n gh_r gh_z gh_n] (6x128)
// ---------------------------------------------------------------------------
__launch_bounds__(256)
__global__ void gates_kernel(const float* __restrict__ Gphi, const float* __restrict__ Gbeta,
                             float* __restrict__ h_phi, float* __restrict__ h_beta)
{
    long long idx = (long long)blockIdx.x * 256 + threadIdx.x;  // < 264192
    const float* G; float* h; int i, jj;
    if (idx < 262144) { i = (int)(idx >> 7); jj = (int)(idx & 127); G = Gphi; h = h_phi; }
    else { int r = (int)(idx - 262144); i = r >> 7; jj = r & 127; G = Gbeta; h = h_beta; }
    const float* g = G + (size_t)i * 768;
    float r_ = sigmoidf_(g[jj] + g[384 + jj]);
    float z_ = sigmoidf_(g[128 + jj] + g[512 + jj]);
    float n_ = tanhf(g[256 + jj] + r_ * g[640 + jj]);
    int hi = i * 128 + jj;
    h[hi] = (1.f - z_) * n_ + z_ * h[hi];
}

// ---------------------------------------------------------------------------
// sample + KLD(gauss): phi blocks 0..1023, beta blocks 1024..1031
// ---------------------------------------------------------------------------
__launch_bounds__(256)
__global__ void sample_kernel(const float* __restrict__ MSphi, const float* __restrict__ MSbeta,
                              const float* __restrict__ epsP, const float* __restrict__ epsB,
                              const float* __restrict__ phiPrior, const float* __restrict__ betaPrior,
                              float* __restrict__ phiS, float* __restrict__ betaS, float* __restrict__ acc)
{
    __shared__ float red[256];
    int tid = threadIdx.x;
    long long idx = (long long)blockIdx.x * 256 + tid;
    float elem; int target;
    if (idx < 262144) {
        int i = (int)(idx >> 7), jj = (int)(idx & 127);
        float mean = MSphi[(size_t)i*256 + jj];
        float stdv = softplusf_(MSphi[(size_t)i*256 + 128 + jj]);
        float sv = mean + stdv * epsP[idx];
        phiS[idx] = sv;
        float d = mean - phiPrior[idx];
        // SIGMA = 1
        elem = -logf(stdv) + 0.5f*(stdv*stdv + d*d) - 0.5f;
        target = 4;
    } else {
        int r = (int)(idx - 262144);
        int i = r >> 7, jj = r & 127;
        float mean = MSbeta[i*256 + jj];
        float stdv = softplusf_(MSbeta[i*256 + 128 + jj]);
        float sv = mean + stdv * epsB[r];
        betaS[r] = sv;
        float d = mean - betaPrior[r];
        // GAMMA = 0.1: 0.5*(2*(log(.1)-log s) + (s^2+d^2)*100 - 1)
        elem = (-2.3025850929940457f - logf(stdv)) + 50.0f*(stdv*stdv + d*d) - 0.5f;
        target = 3;
    }
    red[tid] = elem; __syncthreads();
    for (int st = 128; st > 0; st >>= 1) { if (tid < st) red[tid] += red[tid + st]; __syncthreads(); }
    if (tid == 0) atomicAdd(acc + target, red[0]);
}

// ---------------------------------------------------------------------------
// Mt[n][k] = dot(beta_s[k,:], W_dec[n,:])   (decoder reassociation)
// ---------------------------------------------------------------------------
__launch_bounds__(256)
__global__ void mt_kernel(const float* __restrict__ betaS, const float* __restrict__ W_dec, float* __restrict__ Mt)
{
    int tid = threadIdx.x, wid = tid >> 6, l = tid & 63;
    int n = blockIdx.x * 4 + wid;       // 512 blocks -> n < 2048
    int k = l & 15, q = l >> 4;
    const float* bs = betaS + k*128 + q*32;
    const float* wd = W_dec + (size_t)n*128 + q*32;
    float p = 0.f;
    #pragma unroll
    for (int j = 0; j < 32; ++j) p = fmaf(bs[j], wd[j], p);
    p += __shfl_xor(p, 16);
    p += __shfl_xor(p, 32);
    if (l < 16) Mt[n*16 + l] = p;
}

// ---------------------------------------------------------------------------
// z / kld_z: wave-per-edge. Lane (k=l>>2, q=l&3).
// logits_q[k] = sum_d pw*pc*W_pi[k,d];  prior[k] = sum_d pw*beta_s[k,d]
// three 16-way softmaxes via butterfly shuffles.
// ---------------------------------------------------------------------------
__launch_bounds__(256)
__global__ void z_kernel(const float* __restrict__ phiS, const float* __restrict__ betaS,
                         const float* __restrict__ W_pi, const int* __restrict__ edges_t,
                         const float* __restrict__ u_t, float* __restrict__ Z, float* __restrict__ acc)
{
    __shared__ float Wpi_s[16][132];
    __shared__ float Bs_s[16][132];
    __shared__ float p_buf[4][128];
    __shared__ float w_buf[4][128];
    __shared__ float red[4];
    int tid = threadIdx.x, wid = tid >> 6, l = tid & 63;
    for (int idx = tid; idx < 2048; idx += 256) {
        int k2 = idx >> 7, d2 = idx & 127;
        Wpi_s[k2][d2] = W_pi[idx];
        Bs_s[k2][d2]  = betaS[idx];
    }
    int k = l >> 2, q = l & 3;
    float kz = 0.f;
    int wg = blockIdx.x * 4 + wid;          // 0..4095
    for (int it = 0; it < 4; ++it) {
        int j = wg + 4096 * it;
        int e = j & 8191; int fl = (j < 8192) ? 0 : 1;
        int w = edges_t[e*2 + fl], c = edges_t[e*2 + (fl ^ 1)];
        float pw0 = phiS[w*128 + l],      pw1 = phiS[w*128 + 64 + l];
        float pc0 = phiS[c*128 + l],      pc1 = phiS[c*128 + 64 + l];
        __syncthreads();
        p_buf[wid][l] = pw0 * pc0; p_buf[wid][64 + l] = pw1 * pc1;
        w_buf[wid][l] = pw0;       w_buf[wid][64 + l] = pw1;
        __syncthreads();
        float lq = 0.f, lp = 0.f;
        #pragma unroll
        for (int jj = 0; jj < 32; ++jj) {
            int d = q + 4*jj;
            lq = fmaf(p_buf[wid][d], Wpi_s[k][d], lq);
            lp = fmaf(w_buf[wid][d], Bs_s[k][d], lp);
        }
        lq += __shfl_xor(lq, 1); lq += __shfl_xor(lq, 2);
        lp += __shfl_xor(lp, 1); lp += __shfl_xor(lp, 2);
        // posterior log-softmax
        float mq = lq;
        mq = fmaxf(mq, __shfl_xor(mq, 4));  mq = fmaxf(mq, __shfl_xor(mq, 8));
        mq = fmaxf(mq, __shfl_xor(mq, 16)); mq = fmaxf(mq, __shfl_xor(mq, 32));
        float eq = expf(lq - mq);
        float sq = eq;
        sq += __shfl_xor(sq, 4); sq += __shfl_xor(sq, 8); sq += __shfl_xor(sq, 16); sq += __shfl_xor(sq, 32);
        float logpost = lq - mq - logf(sq);
        float post = eq / sq;
        // prior log-softmax
        float mp = lp;
        mp = fmaxf(mp, __shfl_xor(mp, 4));  mp = fmaxf(mp, __shfl_xor(mp, 8));
        mp = fmaxf(mp, __shfl_xor(mp, 16)); mp = fmaxf(mp, __shfl_xor(mp, 32));
        float ep = expf(lp - mp);
        float sp = ep;
        sp += __shfl_xor(sp, 4); sp += __shfl_xor(sp, 8); sp += __shfl_xor(sp, 16); sp += __shfl_xor(sp, 32);
        float logprior = lp - mp - logf(sp);
        float v = post * (logpost - logprior);
        v += __shfl_xor(v, 4); v += __shfl_xor(v, 8); v += __shfl_xor(v, 16); v += __shfl_xor(v, 32);
        kz += v;
        // gumbel-softmax sample
        float u = u_t[(size_t)j*16 + k];
        float g = -logf(-logf(u + 1e-10f) + 1e-10f);
        float zl = lq + g;
        float mz = zl;
        mz = fmaxf(mz, __shfl_xor(mz, 4));  mz = fmaxf(mz, __shfl_xor(mz, 8));
        mz = fmaxf(mz, __shfl_xor(mz, 16)); mz = fmaxf(mz, __shfl_xor(mz, 32));
        float ez = expf(zl - mz);
        float sz = ez;
        sz += __shfl_xor(sz, 4); sz += __shfl_xor(sz, 8); sz += __shfl_xor(sz, 16); sz += __shfl_xor(sz, 32);
        if (q == 0) Z[(size_t)j*16 + k] = ez / sz;
    }
    if (l == 0) red[wid] = kz;
    __syncthreads();
    if (tid == 0) atomicAdd(acc + 1, red[0] + red[1] + red[2] + red[3]);
}

// ---------------------------------------------------------------------------
// nll: recon[j,n] = sum_k z[j,k]*Mt[n][k]; nll_j = logsumexp_n - recon[j,c].
// Mt register-resident: thread owns 4 cols x 16 k. 512 thr, 32 edges/block.
// ---------------------------------------------------------------------------
__launch_bounds__(512)
__global__ void nll_kernel(const float* __restrict__ Mt, const float* __restrict__ Z,
                           const int* __restrict__ edges_t, float* __restrict__ acc)
{
    __shared__ float sm[8][8], ss[8][8], sc[8][8];   // [edge-in-round][wave]
    __shared__ float fin[8];
    int tid = threadIdx.x, wid = tid >> 6, l = tid & 63;
    float mreg[4][16];
    #pragma unroll
    for (int cc = 0; cc < 4; ++cc) {
        const float* mp = Mt + (size_t)(tid*4 + cc) * 16;
        #pragma unroll
        for (int kk = 0; kk < 16; ++kk) mreg[cc][kk] = mp[kk];
    }
    float nll = 0.f;
    for (int r8 = 0; r8 < 4; ++r8) {
        #pragma unroll
        for (int e8 = 0; e8 < 8; ++e8) {
            int j = blockIdx.x * 32 + r8 * 8 + e8;
            int e = j & 8191; int fl = (j < 8192) ? 0 : 1;
            int c = edges_t[e*2 + (fl ^ 1)];
            float zk[16];
            #pragma unroll
            for (int kk = 0; kk < 16; ++kk) zk[kk] = Z[(size_t)j*16 + kk];
            float m = -1e30f, s = 0.f, cv = 0.f;
            #pragma unroll
            for (int cc = 0; cc < 4; ++cc) {
                float v = 0.f;
                #pragma unroll
                for (int kk = 0; kk < 16; ++kk) v = fmaf(zk[kk], mreg[cc][kk], v);
                if (tid*4 + cc == c) cv = v;
                if (v > m) { s = s * expf(m - v) + 1.f; m = v; }
                else s += expf(v - m);
            }
            #pragma unroll
            for (int mask = 1; mask < 64; mask <<= 1) {
                float m2 = __shfl_xor(m, mask);
                float s2 = __shfl_xor(s, mask);
                float c2 = __shfl_xor(cv, mask);
                float mo = fmaxf(m, m2);
                s = s * expf(m - mo) + s2 * expf(m2 - mo);
                m = mo; cv += c2;
            }
            if (l == 0) { sm[e8][wid] = m; ss[e8][wid] = s; sc[e8][wid] = cv; }
        }
        __syncthreads();
        if (tid < 8) {
            float M = sm[tid][0];
            #pragma unroll
            for (int w2 = 1; w2 < 8; ++w2) M = fmaxf(M, sm[tid][w2]);
            float S = 0.f, CV = 0.f;
            #pragma unroll
            for (int w2 = 0; w2 < 8; ++w2) { S += ss[tid][w2] * expf(sm[tid][w2] - M); CV += sc[tid][w2]; }
            nll += M + logf(S) - CV;
        }
        __syncthreads();
    }
    if (tid < 8) fin[tid] = nll;
    __syncthreads();
    if (tid == 0) {
        float t = 0.f;
        #pragma unroll
        for (int q2 = 0; q2 < 8; ++q2) t += fin[q2];
        atomicAdd(acc + 0, t);
    }
}

__global__ void final_kernel(const float* __restrict__ acc, float* __restrict__ out)
{
    if (threadIdx.x == 0 && blockIdx.x == 0) {
        out[0] = acc[0] / CNT;
        out[1] = acc[1] / CNT;
        out[2] = 16.f * acc[2] / CNT;
        out[3] = acc[3] / CNT;
        out[4] = acc[4] / CNT;
    }
}

// ---------------------------------------------------------------------------
extern "C" void kernel_launch(void* const* d_in, const int* in_sizes, int n_in,
                              void* d_out, int out_size, void* d_ws, size_t ws_size,
                              hipStream_t stream)
{
    (void)in_sizes; (void)n_in; (void)out_size; (void)ws_size;
    const int*   edges   = (const int*)d_in[0];
    const int*   sidx    = (const int*)d_in[1];
    const float* eps_phi = (const float*)d_in[2];
    const float* eps_beta= (const float*)d_in[3];
    const float* u_g     = (const float*)d_in[4];
    const float* amE     = (const float*)d_in[5];
    const float* asE     = (const float*)d_in[6];
    const float* W_s2phi = (const float*)d_in[7];
    const float* b_s2phi = (const float*)d_in[8];
    const float* W_s2beta= (const float*)d_in[9];
    const float* b_s2beta= (const float*)d_in[10];
    const float* W_bmean = (const float*)d_in[11];
    const float* b_bmean = (const float*)d_in[12];
    const float* W_bstd  = (const float*)d_in[13];
    const float* b_bstd  = (const float*)d_in[14];
    const float* W_pmean = (const float*)d_in[15];
    const float* b_pmean = (const float*)d_in[16];
    const float* W_pstd  = (const float*)d_in[17];
    const float* b_pstd  = (const float*)d_in[18];
    const float* W_pi    = (const float*)d_in[19];
    const float* Wih_n   = (const float*)d_in[20];
    const float* Whh_n   = (const float*)d_in[21];
    const float* bih_n   = (const float*)d_in[22];
    const float* bhh_n   = (const float*)d_in[23];
    const float* Wih_c   = (const float*)d_in[24];
    const float* Whh_c   = (const float*)d_in[25];
    const float* bih_c   = (const float*)d_in[26];
    const float* bhh_c   = (const float*)d_in[27];
    const float* W_dec   = (const float*)d_in[28];

    float* ws     = (float*)d_ws;
    float* Bg_n   = ws;                    // 98304
    float* Bg_c   = Bg_n   + 98304;        // 98304
    float* Bms_n  = Bg_c   + 98304;        // 32768
    float* Bms_c  = Bms_n  + 32768;        // 32768
    float* a_m    = Bms_c  + 32768;        // 128
    float* phiA   = a_m    + 128;          // 262144
    float* phiB   = phiA   + 262144;       // 262144
    float* h_phi  = phiB   + 262144;       // 262144
    float* betaA  = h_phi  + 262144;       // 2048
    float* betaB  = betaA  + 2048;         // 2048
    float* h_beta = betaB  + 2048;         // 2048
    float* Gphi   = h_beta + 2048;         // 1572864
    float* Gbeta  = Gphi   + 1572864;      // 12288
    float* MSphi  = Gbeta  + 12288;        // 524288
    float* MSbeta = MSphi  + 524288;       // 4096
    float* Mt     = MSbeta + 4096;         // 32768
    float* Zb     = Mt     + 32768;        // 262144
    float* acc    = Zb     + 262144;       // 8

    hipMemsetAsync(h_phi,  0, 262144 * sizeof(float), stream);
    hipMemsetAsync(h_beta, 0, 2048 * sizeof(float), stream);
    hipMemsetAsync(acc,    0, 8 * sizeof(float), stream);

    prep_kernel<<<1024, 256, 0, stream>>>(Wih_n, Whh_n, Wih_c, Whh_c,
                                          W_pmean, W_pstd, W_bmean, W_bstd,
                                          Bg_n, Bg_c, Bms_n, Bms_c);
    alpha_kernel<<<1, 128, 0, stream>>>(amE, asE, sidx, a_m, acc);
    phi0_kernel<<<66048, 256, 0, stream>>>(W_s2phi, b_s2phi, W_s2beta, b_s2beta, a_m, phiA, betaA);

    float* phiPrior = phiA;  float* phiS = phiB;
    float* betaPrior = betaA; float* betaS = betaB;
    for (int t = 0; t < TT; ++t) {
        // gates: cols 0..383 = phi_prior @ Wsum^T + bih ; 384..767 = h @ Whh^T + bhh
        gemm_bias<<<dim3(12, 33), 256, 0, stream>>>(phiPrior, h_phi, betaPrior, h_beta,
                                                    Bg_n, Bg_c, bih_n, bhh_n, bih_c, bhh_c,
                                                    Gphi, Gbeta, 768, 384, 32, 16);
        gates_kernel<<<1032, 256, 0, stream>>>(Gphi, Gbeta, h_phi, h_beta);
        // mean/std: cols 0..127 = mean, 128..255 = std pre-activation
        gemm_bias<<<dim3(4, 33), 256, 0, stream>>>(h_phi, h_phi, h_beta, h_beta,
                                                   Bms_n, Bms_c, b_pmean, b_pstd, b_bmean, b_bstd,
                                                   MSphi, MSbeta, 256, 128, 32, 16);
        sample_kernel<<<1032, 256, 0, stream>>>(MSphi, MSbeta,
                                                eps_phi + (size_t)t * 262144, eps_beta + (size_t)t * 2048,
                                                phiPrior, betaPrior, phiS, betaS, acc);
        mt_kernel<<<512, 256, 0, stream>>>(betaS, W_dec, Mt);
        z_kernel<<<1024, 256, 0, stream>>>(phiS, betaS, W_pi,
                                           edges + (size_t)t * EE * 2, u_g + (size_t)t * TWOE * KK, Zb, acc);
        nll_kernel<<<512, 512, 0, stream>>>(Mt, Zb, edges + (size_t)t * EE * 2, acc);
        float* tp = phiPrior; phiPrior = phiS; phiS = tp;
        float* tb = betaPrior; betaPrior = betaS; betaS = tb;
    }
    final_kernel<<<1, 64, 0, stream>>>(acc, (float*)d_out);
}

// Round 4
// 2682.228 us; speedup vs baseline: 1.1098x; 1.1098x over previous
//
#include <hip/hip_runtime.h>

// Problem constants
#define NN 2048
#define DD 128
#define KK 16
#define TT 16
#define EE 8192
#define TWOE 16384
#define CNT 262144.0f   // T * 2E

#define LOG2E 1.4426950408889634f
#define LN2   0.6931471805599453f

// raw hw transcendentals: v_exp_f32 (2^x) and v_log_f32 (log2 x)
__device__ __forceinline__ float exp2_(float x) { return __builtin_amdgcn_exp2f(x); }
__device__ __forceinline__ float log2_(float x) { return __builtin_amdgcn_logf(x); }
__device__ __forceinline__ float expf_(float x) { return exp2_(x * LOG2E); }
__device__ __forceinline__ float logf_(float x) { return log2_(x) * LN2; }
__device__ __forceinline__ float sigmoidf_(float x) { return 1.f / (1.f + expf_(-x)); }
__device__ __forceinline__ float softplusf_(float x) { return fmaxf(x, 0.f) + logf_(1.f + expf_(-fabsf(x))); }
__device__ __forceinline__ float tanhf_(float x) { return 1.f - 2.f / (1.f + expf_(2.f * x)); }

#define D4(a,b) ((a).x*(b).x + (a).y*(b).y + (a).z*(b).z + (a).w*(b).w)

// ---------------------------------------------------------------------------
// Init: build concatenated weight matrices
//  Bg  [768x128]: rows 0..383 = Wih[:, :128]+Wih[:,128:], rows 384..767 = Whh
//  Bms [256x128]: rows 0..127 = W_mean, rows 128..255 = W_std
// ---------------------------------------------------------------------------
__launch_bounds__(256)
__global__ void prep_kernel(const float* __restrict__ Wih_n, const float* __restrict__ Whh_n,
                            const float* __restrict__ Wih_c, const float* __restrict__ Whh_c,
                            const float* __restrict__ W_pmean, const float* __restrict__ W_pstd,
                            const float* __restrict__ W_bmean, const float* __restrict__ W_bstd,
                            float* __restrict__ Bg_n, float* __restrict__ Bg_c,
                            float* __restrict__ Bms_n, float* __restrict__ Bms_c)
{
    int idx = blockIdx.x * 256 + threadIdx.x;   // < 262144
    if (idx < 98304) {
        int r = idx;
        if (r < 49152) { int j = r >> 7, k2 = r & 127; Bg_n[r] = Wih_n[j*256 + k2] + Wih_n[j*256 + 128 + k2]; }
        else Bg_n[r] = Whh_n[r - 49152];
    } else if (idx < 196608) {
        int r = idx - 98304;
        if (r < 49152) { int j = r >> 7, k2 = r & 127; Bg_c[r] = Wih_c[j*256 + k2] + Wih_c[j*256 + 128 + k2]; }
        else Bg_c[r] = Whh_c[r - 49152];
    } else if (idx < 229376) {
        int r = idx - 196608;
        Bms_n[r] = (r < 16384) ? W_pmean[r] : W_pstd[r - 16384];
    } else {
        int r = idx - 229376;
        Bms_c[r] = (r < 16384) ? W_bmean[r] : W_bstd[r - 16384];
    }
}

// ---------------------------------------------------------------------------
// alpha: a_m, kld_alpha
// ---------------------------------------------------------------------------
__launch_bounds__(128)
__global__ void alpha_kernel(const float* __restrict__ amE, const float* __restrict__ asE,
                             const int* __restrict__ sidx, float* __restrict__ a_m, float* __restrict__ acc)
{
    __shared__ float red[128];
    int d = threadIdx.x;
    int s = sidx[0];
    float am = amE[s*128 + d];
    float as = softplusf_(asE[s*128 + d]);
    a_m[d] = am;
    float e = -logf_(as) + 0.5f*(as*as + am*am) - 0.5f;
    red[d] = e; __syncthreads();
    for (int st = 64; st > 0; st >>= 1) { if (d < st) red[d] += red[d + st]; __syncthreads(); }
    if (d == 0) acc[2] = red[0];
}

// ---------------------------------------------------------------------------
// phi0/beta0 GEMV
// ---------------------------------------------------------------------------
__launch_bounds__(256)
__global__ void phi0_kernel(const float* __restrict__ Wp, const float* __restrict__ bp,
                            const float* __restrict__ Wb, const float* __restrict__ bb,
                            const float* __restrict__ a_m, float* __restrict__ phi0, float* __restrict__ beta0)
{
    int wid = threadIdx.x >> 6, l = threadIdx.x & 63;
    long long row = (long long)blockIdx.x * 4 + wid;     // < 264192
    const float* W; const float* b; float* o; long long r = row;
    if (row < 262144) { W = Wp; b = bp; o = phi0; }
    else { W = Wb; b = bb; o = beta0; r = row - 262144; }
    const float* wr = W + r * 128;
    float acc = a_m[l] * wr[l] + a_m[64 + l] * wr[64 + l];
    #pragma unroll
    for (int m = 32; m >= 1; m >>= 1) acc += __shfl_xor(acc, m);
    if (l == 0) o[r] = acc + b[r];
}

// ---------------------------------------------------------------------------
// Generic tiled SGEMM
// ---------------------------------------------------------------------------
__launch_bounds__(256)
__global__ void gemm_bias(const float* __restrict__ Ap1, const float* __restrict__ Ap2,
                          const float* __restrict__ Ab1, const float* __restrict__ Ab2,
                          const float* __restrict__ Bphi, const float* __restrict__ Bbeta,
                          const float* __restrict__ b0p, const float* __restrict__ b1p,
                          const float* __restrict__ b0b, const float* __restrict__ b1b,
                          float* __restrict__ Cphi, float* __restrict__ Cbeta,
                          int Ncols, int Nsplit, int MtPhi, int Mbeta)
{
    __shared__ float As[32][68];
    __shared__ float Bs[32][68];
    bool isBeta = (blockIdx.y == (unsigned)MtPhi);
    int n0 = blockIdx.x * 64;
    const float* A = isBeta ? ((n0 >= Nsplit) ? Ab2 : Ab1) : ((n0 >= Nsplit) ? Ap2 : Ap1);
    const float* B = isBeta ? Bbeta : Bphi;
    const float* b0 = isBeta ? b0b : b0p;
    const float* b1 = isBeta ? b1b : b1p;
    float* C = isBeta ? Cbeta : Cphi;
    int M = isBeta ? Mbeta : MtPhi * 64;
    int m0 = isBeta ? 0 : blockIdx.y * 64;
    int tid = threadIdx.x;
    int tx = tid & 15, ty = tid >> 4;
    float accu[4][4] = {};
    int lr = tid >> 2;          // 0..63
    int lk = (tid & 3) * 8;     // 0,8,16,24
    for (int k0 = 0; k0 < 128; k0 += 32) {
        int arow = m0 + lr;
        const float* ap = A + (size_t)arow * 128 + k0 + lk;
        const float* bp = B + (size_t)(n0 + lr) * 128 + k0 + lk;
        #pragma unroll
        for (int qq = 0; qq < 8; ++qq) {
            As[lk + qq][lr] = (arow < M) ? ap[qq] : 0.f;
            Bs[lk + qq][lr] = bp[qq];
        }
        __syncthreads();
        #pragma unroll
        for (int kk = 0; kk < 32; ++kk) {
            float av[4], bv[4];
            #pragma unroll
            for (int i2 = 0; i2 < 4; ++i2) av[i2] = As[kk][ty*4 + i2];
            #pragma unroll
            for (int j2 = 0; j2 < 4; ++j2) bv[j2] = Bs[kk][tx*4 + j2];
            #pragma unroll
            for (int i2 = 0; i2 < 4; ++i2)
                #pragma unroll
                for (int j2 = 0; j2 < 4; ++j2)
                    accu[i2][j2] = fmaf(av[i2], bv[j2], accu[i2][j2]);
        }
        __syncthreads();
    }
    #pragma unroll
    for (int i2 = 0; i2 < 4; ++i2) {
        int row = m0 + ty*4 + i2;
        if (row >= M) continue;
        #pragma unroll
        for (int j2 = 0; j2 < 4; ++j2) {
            int col = n0 + tx*4 + j2;
            float bv = (col < Nsplit) ? b0[col] : b1[col - Nsplit];
            C[(size_t)row * Ncols + col] = accu[i2][j2] + bv;
        }
    }
}

// ---------------------------------------------------------------------------
// GRU gate elementwise
// ---------------------------------------------------------------------------
__launch_bounds__(256)
__global__ void gates_kernel(const float* __restrict__ Gphi, const float* __restrict__ Gbeta,
                             float* __restrict__ h_phi, float* __restrict__ h_beta)
{
    long long idx = (long long)blockIdx.x * 256 + threadIdx.x;  // < 264192
    const float* G; float* h; int i, jj;
    if (idx < 262144) { i = (int)(idx >> 7); jj = (int)(idx & 127); G = Gphi; h = h_phi; }
    else { int r = (int)(idx - 262144); i = r >> 7; jj = r & 127; G = Gbeta; h = h_beta; }
    const float* g = G + (size_t)i * 768;
    float r_ = sigmoidf_(g[jj] + g[384 + jj]);
    float z_ = sigmoidf_(g[128 + jj] + g[512 + jj]);
    float n_ = tanhf_(g[256 + jj] + r_ * g[640 + jj]);
    int hi = i * 128 + jj;
    h[hi] = (1.f - z_) * n_ + z_ * h[hi];
}

// ---------------------------------------------------------------------------
// sample + KLD(gauss)
// ---------------------------------------------------------------------------
__launch_bounds__(256)
__global__ void sample_kernel(const float* __restrict__ MSphi, const float* __restrict__ MSbeta,
                              const float* __restrict__ epsP, const float* __restrict__ epsB,
                              const float* __restrict__ phiPrior, const float* __restrict__ betaPrior,
                              float* __restrict__ phiS, float* __restrict__ betaS, float* __restrict__ acc)
{
    __shared__ float red[256];
    int tid = threadIdx.x;
    long long idx = (long long)blockIdx.x * 256 + tid;
    float elem; int target;
    if (idx < 262144) {
        int i = (int)(idx >> 7), jj = (int)(idx & 127);
        float mean = MSphi[(size_t)i*256 + jj];
        float stdv = softplusf_(MSphi[(size_t)i*256 + 128 + jj]);
        float sv = mean + stdv * epsP[idx];
        phiS[idx] = sv;
        float d = mean - phiPrior[idx];
        elem = -logf_(stdv) + 0.5f*(stdv*stdv + d*d) - 0.5f;
        target = 4;
    } else {
        int r = (int)(idx - 262144);
        int i = r >> 7, jj = r & 127;
        float mean = MSbeta[i*256 + jj];
        float stdv = softplusf_(MSbeta[i*256 + 128 + jj]);
        float sv = mean + stdv * epsB[r];
        betaS[r] = sv;
        float d = mean - betaPrior[r];
        elem = (-2.3025850929940457f - logf_(stdv)) + 50.0f*(stdv*stdv + d*d) - 0.5f;
        target = 3;
    }
    red[tid] = elem; __syncthreads();
    for (int st = 128; st > 0; st >>= 1) { if (tid < st) red[tid] += red[tid + st]; __syncthreads(); }
    if (tid == 0) atomicAdd(acc + target, red[0]);
}

// ---------------------------------------------------------------------------
// Mt[n][k] = dot(beta_s[k,:], W_dec[n,:]) * LOG2E   (pre-scaled for exp2)
// ---------------------------------------------------------------------------
__launch_bounds__(256)
__global__ void mt_kernel(const float* __restrict__ betaS, const float* __restrict__ W_dec, float* __restrict__ Mt)
{
    int tid = threadIdx.x, wid = tid >> 6, l = tid & 63;
    int n = blockIdx.x * 4 + wid;       // 512 blocks -> n < 2048
    int k = l & 15, q = l >> 4;
    const float* bs = betaS + k*128 + q*32;
    const float* wd = W_dec + (size_t)n*128 + q*32;
    float p = 0.f;
    #pragma unroll
    for (int j = 0; j < 32; ++j) p = fmaf(bs[j], wd[j], p);
    p += __shfl_xor(p, 16);
    p += __shfl_xor(p, 32);
    if (l < 16) Mt[n*16 + l] = p * LOG2E;
}

// ---------------------------------------------------------------------------
// z / kld_z v2: lane (k = l>>2, q = l&3) owns d-range [q*32, q*32+32).
// W_pi / beta_s rows held in registers; phi chunks loaded float4 from global.
// No LDS, no __syncthreads. Prior softmax keeps max (lp can be large);
// posterior & gumbel skip max (bounded).
// ---------------------------------------------------------------------------
#define ZSTEP(A,B,Wv,Bv) { float4 a_=(A), b_=(B); \
    lp += a_.x*(Bv).x + a_.y*(Bv).y + a_.z*(Bv).z + a_.w*(Bv).w; \
    lq += (a_.x*b_.x)*(Wv).x + (a_.y*b_.y)*(Wv).y + (a_.z*b_.z)*(Wv).z + (a_.w*b_.w)*(Wv).w; }

__launch_bounds__(256, 3)
__global__ void z_kernel(const float* __restrict__ phiS, const float* __restrict__ betaS,
                         const float* __restrict__ W_pi, const int* __restrict__ edges_t,
                         const float* __restrict__ u_t, float* __restrict__ Z, float* __restrict__ acc)
{
    int tid = threadIdx.x, wid = tid >> 6, l = tid & 63;
    int k = l >> 2, q = l & 3;
    int d0 = q * 32;
    const float4* wp = (const float4*)(W_pi  + k*128 + d0);
    const float4* bp = (const float4*)(betaS + k*128 + d0);
    float4 wr0 = wp[0], wr1 = wp[1], wr2 = wp[2], wr3 = wp[3],
           wr4 = wp[4], wr5 = wp[5], wr6 = wp[6], wr7 = wp[7];
    float4 br0 = bp[0], br1 = bp[1], br2 = bp[2], br3 = bp[3],
           br4 = bp[4], br5 = bp[5], br6 = bp[6], br7 = bp[7];
    float kz = 0.f;
    int gw = blockIdx.x * 4 + wid;          // 0..2047
    for (int it = 0; it < 8; ++it) {
        int j = gw * 8 + it;                // 0..16383
        int e = j & 8191; int fl = j >> 13;
        int w = edges_t[e*2 + fl], c = edges_t[e*2 + (fl ^ 1)];
        const float4* pw4 = (const float4*)(phiS + w*128 + d0);
        const float4* pc4 = (const float4*)(phiS + c*128 + d0);
        float lq = 0.f, lp = 0.f;
        ZSTEP(pw4[0], pc4[0], wr0, br0); ZSTEP(pw4[1], pc4[1], wr1, br1);
        ZSTEP(pw4[2], pc4[2], wr2, br2); ZSTEP(pw4[3], pc4[3], wr3, br3);
        ZSTEP(pw4[4], pc4[4], wr4, br4); ZSTEP(pw4[5], pc4[5], wr5, br5);
        ZSTEP(pw4[6], pc4[6], wr6, br6); ZSTEP(pw4[7], pc4[7], wr7, br7);
        lq += __shfl_xor(lq, 1); lq += __shfl_xor(lq, 2);
        lp += __shfl_xor(lp, 1); lp += __shfl_xor(lp, 2);
        // posterior log-softmax (no max: |lq| bounded ~15)
        float eq = expf_(lq);
        float sq = eq;
        sq += __shfl_xor(sq, 4); sq += __shfl_xor(sq, 8); sq += __shfl_xor(sq, 16); sq += __shfl_xor(sq, 32);
        float rsq = __builtin_amdgcn_rcpf(sq);
        float logpost = lq - logf_(sq);
        float post = eq * rsq;
        // prior log-softmax (keep max: lp can be large)
        float mp = lp;
        mp = fmaxf(mp, __shfl_xor(mp, 4));  mp = fmaxf(mp, __shfl_xor(mp, 8));
        mp = fmaxf(mp, __shfl_xor(mp, 16)); mp = fmaxf(mp, __shfl_xor(mp, 32));
        float ep = expf_(lp - mp);
        float sp = ep;
        sp += __shfl_xor(sp, 4); sp += __shfl_xor(sp, 8); sp += __shfl_xor(sp, 16); sp += __shfl_xor(sp, 32);
        float logprior = (lp - mp) - logf_(sp);
        float v = post * (logpost - logprior);
        v += __shfl_xor(v, 4); v += __shfl_xor(v, 8); v += __shfl_xor(v, 16); v += __shfl_xor(v, 32);
        kz += v;
        // gumbel-softmax sample (no max: zl <= lq + 23)
        float u = u_t[(size_t)j*16 + k];
        float g = -logf_(-logf_(u + 1e-10f) + 1e-10f);
        float zl = lq + g;
        float ez = expf_(zl);
        float sz = ez;
        sz += __shfl_xor(sz, 4); sz += __shfl_xor(sz, 8); sz += __shfl_xor(sz, 16); sz += __shfl_xor(sz, 32);
        if (q == 0) Z[(size_t)j*16 + k] = ez * __builtin_amdgcn_rcpf(sz);
    }
    if (l == 0) atomicAdd(acc + 1, kz);
}

// ---------------------------------------------------------------------------
// nll v2: recon[j,n] = sum_k z[j,k]*Mt[n][k] (Mt pre-scaled by log2e).
// Thread owns 4 cols x 16 k in explicit float4 registers. No max subtraction
// (logits bounded: z convex combo of Mt rows). One barrier per block.
// ---------------------------------------------------------------------------
__launch_bounds__(512, 3)
__global__ void nll_kernel(const float* __restrict__ Mt, const float* __restrict__ Z,
                           const int* __restrict__ edges_t, float* __restrict__ acc)
{
    __shared__ float ss[32][8], sc[32][8];
    int tid = threadIdx.x, wid = tid >> 6, l = tid & 63;
    int n0 = tid * 4;
    const float4* mp = (const float4*)(Mt + (size_t)n0 * 16);
    float4 M0 = mp[0],  M1 = mp[1],  M2 = mp[2],  M3 = mp[3];
    float4 M4 = mp[4],  M5 = mp[5],  M6 = mp[6],  M7 = mp[7];
    float4 M8 = mp[8],  M9 = mp[9],  M10 = mp[10], M11 = mp[11];
    float4 M12 = mp[12], M13 = mp[13], M14 = mp[14], M15 = mp[15];
    for (int e = 0; e < 32; ++e) {
        int j = blockIdx.x * 32 + e;
        int ei = j & 8191; int fl = j >> 13;
        int c = edges_t[ei*2 + (fl ^ 1)];
        const float4* zp = (const float4*)(Z + (size_t)j * 16);
        float4 Z0 = zp[0], Z1 = zp[1], Z2 = zp[2], Z3 = zp[3];
        float v0 = D4(Z0, M0)  + D4(Z1, M1)  + D4(Z2, M2)  + D4(Z3, M3);
        float v1 = D4(Z0, M4)  + D4(Z1, M5)  + D4(Z2, M6)  + D4(Z3, M7);
        float v2 = D4(Z0, M8)  + D4(Z1, M9)  + D4(Z2, M10) + D4(Z3, M11);
        float v3 = D4(Z0, M12) + D4(Z1, M13) + D4(Z2, M14) + D4(Z3, M15);
        float s = exp2_(v0) + exp2_(v1) + exp2_(v2) + exp2_(v3);
        float cv = 0.f;
        cv = (c == n0    ) ? v0 : cv;
        cv = (c == n0 + 1) ? v1 : cv;
        cv = (c == n0 + 2) ? v2 : cv;
        cv = (c == n0 + 3) ? v3 : cv;
        #pragma unroll
        for (int m = 1; m < 64; m <<= 1) {
            s  += __shfl_xor(s, m);
            cv += __shfl_xor(cv, m);
        }
        if (l == 0) { ss[e][wid] = s; sc[e][wid] = cv; }
    }
    __syncthreads();
    float val = 0.f;
    if (tid < 32) {
        float S = 0.f, CV = 0.f;
        #pragma unroll
        for (int w2 = 0; w2 < 8; ++w2) { S += ss[tid][w2]; CV += sc[tid][w2]; }
        val = LN2 * (log2_(S) - CV);
    }
    if (tid < 64) {
        #pragma unroll
        for (int m = 1; m < 64; m <<= 1) val += __shfl_xor(val, m);
        if (tid == 0) atomicAdd(acc + 0, val);
    }
}

__global__ void final_kernel(const float* __restrict__ acc, float* __restrict__ out)
{
    if (threadIdx.x == 0 && blockIdx.x == 0) {
        out[0] = acc[0] / CNT;
        out[1] = acc[1] / CNT;
        out[2] = 16.f * acc[2] / CNT;
        out[3] = acc[3] / CNT;
        out[4] = acc[4] / CNT;
    }
}

// ---------------------------------------------------------------------------
extern "C" void kernel_launch(void* const* d_in, const int* in_sizes, int n_in,
                              void* d_out, int out_size, void* d_ws, size_t ws_size,
                              hipStream_t stream)
{
    (void)in_sizes; (void)n_in; (void)out_size; (void)ws_size;
    const int*   edges   = (const int*)d_in[0];
    const int*   sidx    = (const int*)d_in[1];
    const float* eps_phi = (const float*)d_in[2];
    const float* eps_beta= (const float*)d_in[3];
    const float* u_g     = (const float*)d_in[4];
    const float* amE     = (const float*)d_in[5];
    const float* asE     = (const float*)d_in[6];
    const float* W_s2phi = (const float*)d_in[7];
    const float* b_s2phi = (const float*)d_in[8];
    const float* W_s2beta= (const float*)d_in[9];
    const float* b_s2beta= (const float*)d_in[10];
    const float* W_bmean = (const float*)d_in[11];
    const float* b_bmean = (const float*)d_in[12];
    const float* W_bstd  = (const float*)d_in[13];
    const float* b_bstd  = (const float*)d_in[14];
    const float* W_pmean = (const float*)d_in[15];
    const float* b_pmean = (const float*)d_in[16];
    const float* W_pstd  = (const float*)d_in[17];
    const float* b_pstd  = (const float*)d_in[18];
    const float* W_pi    = (const float*)d_in[19];
    const float* Wih_n   = (const float*)d_in[20];
    const float* Whh_n   = (const float*)d_in[21];
    const float* bih_n   = (const float*)d_in[22];
    const float* bhh_n   = (const float*)d_in[23];
    const float* Wih_c   = (const float*)d_in[24];
    const float* Whh_c   = (const float*)d_in[25];
    const float* bih_c   = (const float*)d_in[26];
    const float* bhh_c   = (const float*)d_in[27];
    const float* W_dec   = (const float*)d_in[28];

    float* ws     = (float*)d_ws;
    float* Bg_n   = ws;                    // 98304
    float* Bg_c   = Bg_n   + 98304;        // 98304
    float* Bms_n  = Bg_c   + 98304;        // 32768
    float* Bms_c  = Bms_n  + 32768;        // 32768
    float* a_m    = Bms_c  + 32768;        // 128
    float* phiA   = a_m    + 128;          // 262144
    float* phiB   = phiA   + 262144;       // 262144
    float* h_phi  = phiB   + 262144;       // 262144
    float* betaA  = h_phi  + 262144;       // 2048
    float* betaB  = betaA  + 2048;         // 2048
    float* h_beta = betaB  + 2048;         // 2048
    float* Gphi   = h_beta + 2048;         // 1572864
    float* Gbeta  = Gphi   + 1572864;      // 12288
    float* MSphi  = Gbeta  + 12288;        // 524288
    float* MSbeta = MSphi  + 524288;       // 4096
    float* Mt     = MSbeta + 4096;         // 32768
    float* Zb     = Mt     + 32768;        // 262144
    float* acc    = Zb     + 262144;       // 8

    (void)hipMemsetAsync(h_phi,  0, 262144 * sizeof(float), stream);
    (void)hipMemsetAsync(h_beta, 0, 2048 * sizeof(float), stream);
    (void)hipMemsetAsync(acc,    0, 8 * sizeof(float), stream);

    prep_kernel<<<1024, 256, 0, stream>>>(Wih_n, Whh_n, Wih_c, Whh_c,
                                          W_pmean, W_pstd, W_bmean, W_bstd,
                                          Bg_n, Bg_c, Bms_n, Bms_c);
    alpha_kernel<<<1, 128, 0, stream>>>(amE, asE, sidx, a_m, acc);
    phi0_kernel<<<66048, 256, 0, stream>>>(W_s2phi, b_s2phi, W_s2beta, b_s2beta, a_m, phiA, betaA);

    float* phiPrior = phiA;  float* phiS = phiB;
    float* betaPrior = betaA; float* betaS = betaB;
    for (int t = 0; t < TT; ++t) {
        gemm_bias<<<dim3(12, 33), 256, 0, stream>>>(phiPrior, h_phi, betaPrior, h_beta,
                                                    Bg_n, Bg_c, bih_n, bhh_n, bih_c, bhh_c,
                                                    Gphi, Gbeta, 768, 384, 32, 16);
        gates_kernel<<<1032, 256, 0, stream>>>(Gphi, Gbeta, h_phi, h_beta);
        gemm_bias<<<dim3(4, 33), 256, 0, stream>>>(h_phi, h_phi, h_beta, h_beta,
                                                   Bms_n, Bms_c, b_pmean, b_pstd, b_bmean, b_bstd,
                                                   MSphi, MSbeta, 256, 128, 32, 16);
        sample_kernel<<<1032, 256, 0, stream>>>(MSphi, MSbeta,
                                                eps_phi + (size_t)t * 262144, eps_beta + (size_t)t * 2048,
                                                phiPrior, betaPrior, phiS, betaS, acc);
        mt_kernel<<<512, 256, 0, stream>>>(betaS, W_dec, Mt);
        z_kernel<<<512, 256, 0, stream>>>(phiS, betaS, W_pi,
                                          edges + (size_t)t * EE * 2, u_g + (size_t)t * TWOE * KK, Zb, acc);
        nll_kernel<<<512, 512, 0, stream>>>(Mt, Zb, edges + (size_t)t * EE * 2, acc);
        float* tp = phiPrior; phiPrior = phiS; phiS = tp;
        float* tb = betaPrior; betaPrior = betaS; betaS = tb;
    }
    final_kernel<<<1, 64, 0, stream>>>(acc, (float*)d_out);
}

// Round 5
// 2194.330 us; speedup vs baseline: 1.3566x; 1.2223x over previous
//
#include <hip/hip_runtime.h>

// Problem constants
#define NN 2048
#define DD 128
#define KK 16
#define TT 16
#define EE 8192
#define TWOE 16384
#define CNT 262144.0f   // T * 2E

#define LOG2E 1.4426950408889634f
#define LN2   0.6931471805599453f

__device__ __forceinline__ float exp2_(float x) { return __builtin_amdgcn_exp2f(x); }
__device__ __forceinline__ float log2_(float x) { return __builtin_amdgcn_logf(x); }
__device__ __forceinline__ float expf_(float x) { return exp2_(x * LOG2E); }
__device__ __forceinline__ float logf_(float x) { return log2_(x) * LN2; }
__device__ __forceinline__ float sigmoidf_(float x) { return 1.f / (1.f + expf_(-x)); }
__device__ __forceinline__ float softplusf_(float x) { return fmaxf(x, 0.f) + logf_(1.f + expf_(-fabsf(x))); }
__device__ __forceinline__ float tanhf_(float x) { return 1.f - 2.f / (1.f + expf_(2.f * x)); }

#define D4(a,b) ((a).x*(b).x + (a).y*(b).y + (a).z*(b).z + (a).w*(b).w)

// ---------------------------------------------------------------------------
// init: prep concat weights + zero h/acc + alpha. Blocks 0..1023 elementwise,
// block 1024 = alpha. acc[2] written (not zeroed) by alpha only.
// ---------------------------------------------------------------------------
__launch_bounds__(256)
__global__ void init_kernel(const float* __restrict__ Wih_n, const float* __restrict__ Whh_n,
                            const float* __restrict__ Wih_c, const float* __restrict__ Whh_c,
                            const float* __restrict__ W_pmean, const float* __restrict__ W_pstd,
                            const float* __restrict__ W_bmean, const float* __restrict__ W_bstd,
                            float* __restrict__ Bg_n, float* __restrict__ Bg_c,
                            float* __restrict__ Bms_n, float* __restrict__ Bms_c,
                            float* __restrict__ hphiA, float* __restrict__ hbetaA,
                            const float* __restrict__ amE, const float* __restrict__ asE,
                            const int* __restrict__ sidx, float* __restrict__ a_m,
                            float* __restrict__ acc)
{
    if (blockIdx.x == 1024) {
        __shared__ float red[128];
        int d = threadIdx.x;
        if (d < 128) {
            int s = sidx[0];
            float am = amE[s*128 + d];
            float as = softplusf_(asE[s*128 + d]);
            a_m[d] = am;
            red[d] = -logf_(as) + 0.5f*(as*as + am*am) - 0.5f;
        }
        __syncthreads();
        for (int st = 64; st > 0; st >>= 1) { if (d < st) red[d] += red[d + st]; __syncthreads(); }
        if (d == 0) acc[2] = red[0];
        return;
    }
    int idx = blockIdx.x * 256 + threadIdx.x;   // < 262144
    hphiA[idx] = 0.f;
    if (idx < 2048) hbetaA[idx] = 0.f;
    if (idx < 2) { acc[idx] = 0.f; acc[idx + 3] = 0.f; }
    if (idx < 98304) {
        int r = idx;
        if (r < 49152) { int j = r >> 7, k2 = r & 127; Bg_n[r] = Wih_n[j*256 + k2] + Wih_n[j*256 + 128 + k2]; }
        else Bg_n[r] = Whh_n[r - 49152];
    } else if (idx < 196608) {
        int r = idx - 98304;
        if (r < 49152) { int j = r >> 7, k2 = r & 127; Bg_c[r] = Wih_c[j*256 + k2] + Wih_c[j*256 + 128 + k2]; }
        else Bg_c[r] = Whh_c[r - 49152];
    } else if (idx < 229376) {
        int r = idx - 196608;
        Bms_n[r] = (r < 16384) ? W_pmean[r] : W_pstd[r - 16384];
    } else {
        int r = idx - 229376;
        Bms_c[r] = (r < 16384) ? W_bmean[r] : W_bstd[r - 16384];
    }
}

// ---------------------------------------------------------------------------
// phi0/beta0 GEMV (HBM-bound, 134 MB)
// ---------------------------------------------------------------------------
__launch_bounds__(256)
__global__ void phi0_kernel(const float* __restrict__ Wp, const float* __restrict__ bp,
                            const float* __restrict__ Wb, const float* __restrict__ bb,
                            const float* __restrict__ a_m, float* __restrict__ phi0, float* __restrict__ beta0)
{
    int wid = threadIdx.x >> 6, l = threadIdx.x & 63;
    long long row = (long long)blockIdx.x * 4 + wid;     // < 264192
    const float* W; const float* b; float* o; long long r = row;
    if (row < 262144) { W = Wp; b = bp; o = phi0; }
    else { W = Wb; b = bb; o = beta0; r = row - 262144; }
    const float* wr = W + r * 128;
    float acc = a_m[l] * wr[l] + a_m[64 + l] * wr[64 + l];
    #pragma unroll
    for (int m = 32; m >= 1; m >>= 1) acc += __shfl_xor(acc, m);
    if (l == 0) o[r] = acc + b[r];
}

// ---------------------------------------------------------------------------
// Fused GRU: gates GEMM (6 gate groups, col-sliced) + nonlinearity.
// Block: 64 rows x 32 j; thread: 8 contiguous rows (rr*8) x 1 j x 6 gates.
// bx<128: phi (rt=bx>>2, jt=bx&3); bx>=128: beta (4 blocks).
// Reads hOld, writes hNew (ping-pong: other blocks stage-read all 128 cols).
// ---------------------------------------------------------------------------
__launch_bounds__(256)
__global__ void gru_kernel(const float* __restrict__ phiPrior, const float* __restrict__ betaPrior,
                           const float* __restrict__ hPhiOld, float* __restrict__ hPhiNew,
                           const float* __restrict__ hBetaOld, float* __restrict__ hBetaNew,
                           const float* __restrict__ Bg_n, const float* __restrict__ Bg_c,
                           const float* __restrict__ bih_n, const float* __restrict__ bhh_n,
                           const float* __restrict__ bih_c, const float* __restrict__ bhh_c)
{
    __shared__ float Xs[32][64];
    __shared__ float Hs[32][64];
    __shared__ float Ws[32][192];
    int bx = blockIdx.x;
    const float* X; const float* Hold; float* Hnew; const float* Bg; const float* bih; const float* bhh;
    int m0, M, j0;
    if (bx < 128) {
        m0 = (bx >> 2) * 64; j0 = (bx & 3) * 32; M = 2048;
        X = phiPrior; Hold = hPhiOld; Hnew = hPhiNew; Bg = Bg_n; bih = bih_n; bhh = bhh_n;
    } else {
        m0 = 0; j0 = (bx - 128) * 32; M = 16;
        X = betaPrior; Hold = hBetaOld; Hnew = hBetaNew; Bg = Bg_c; bih = bih_c; bhh = bhh_c;
    }
    int tid = threadIdx.x;
    int j  = tid & 31;
    int rr = tid >> 5;            // 0..7 -> rows rr*8..rr*8+7
    float acc[6][8] = {};
    int srow = tid >> 3;          // 0..31
    int skq  = (tid & 7) * 4;
    for (int k0 = 0; k0 < 128; k0 += 32) {
        #pragma unroll
        for (int h2 = 0; h2 < 2; ++h2) {
            int row = srow + 32 * h2;
            int grow = m0 + row;
            float4 xv = make_float4(0.f,0.f,0.f,0.f), hv = xv;
            if (grow < M) {
                xv = *(const float4*)(X    + (size_t)grow*128 + k0 + skq);
                hv = *(const float4*)(Hold + (size_t)grow*128 + k0 + skq);
            }
            Xs[skq+0][row] = xv.x; Xs[skq+1][row] = xv.y; Xs[skq+2][row] = xv.z; Xs[skq+3][row] = xv.w;
            Hs[skq+0][row] = hv.x; Hs[skq+1][row] = hv.y; Hs[skq+2][row] = hv.z; Hs[skq+3][row] = hv.w;
        }
        #pragma unroll
        for (int h6 = 0; h6 < 6; ++h6) {
            int rowIdx = srow + 32 * h6;          // 0..191
            int g = rowIdx >> 5, jj2 = rowIdx & 31;
            float4 wv = *(const float4*)(Bg + (size_t)(g*128 + j0 + jj2)*128 + k0 + skq);
            Ws[skq+0][rowIdx] = wv.x; Ws[skq+1][rowIdx] = wv.y; Ws[skq+2][rowIdx] = wv.z; Ws[skq+3][rowIdx] = wv.w;
        }
        __syncthreads();
        #pragma unroll
        for (int kk = 0; kk < 32; ++kk) {
            float xa[8], ha[8];
            *(float4*)&xa[0] = *(const float4*)&Xs[kk][rr*8];
            *(float4*)&xa[4] = *(const float4*)&Xs[kk][rr*8+4];
            *(float4*)&ha[0] = *(const float4*)&Hs[kk][rr*8];
            *(float4*)&ha[4] = *(const float4*)&Hs[kk][rr*8+4];
            #pragma unroll
            for (int g = 0; g < 3; ++g) {
                float wv = Ws[kk][g*32 + j];
                #pragma unroll
                for (int i = 0; i < 8; ++i) acc[g][i] = fmaf(xa[i], wv, acc[g][i]);
            }
            #pragma unroll
            for (int g = 3; g < 6; ++g) {
                float wv = Ws[kk][g*32 + j];
                #pragma unroll
                for (int i = 0; i < 8; ++i) acc[g][i] = fmaf(ha[i], wv, acc[g][i]);
            }
        }
        __syncthreads();
    }
    float bi_r = bih[j0 + j], bi_z = bih[128 + j0 + j], bi_n = bih[256 + j0 + j];
    float bh_r = bhh[j0 + j], bh_z = bhh[128 + j0 + j], bh_n = bhh[256 + j0 + j];
    #pragma unroll
    for (int i = 0; i < 8; ++i) {
        int row = m0 + rr*8 + i;
        if (row < M) {
            float r_ = sigmoidf_(acc[0][i] + bi_r + acc[3][i] + bh_r);
            float z_ = sigmoidf_(acc[1][i] + bi_z + acc[4][i] + bh_z);
            float n_ = tanhf_(acc[2][i] + bi_n + r_ * (acc[5][i] + bh_n));
            size_t hi = (size_t)row * 128 + j0 + j;
            Hnew[hi] = (1.f - z_) * n_ + z_ * Hold[hi];
        }
    }
}

// ---------------------------------------------------------------------------
// Fused mean/std GEMM + softplus + sample + KLD.
// Block: 64 rows x 32 j, 2 groups (mean/std). Thread: 8 rows x 1 j x 2.
// bx<128: phi; bx 128..131: beta.
// ---------------------------------------------------------------------------
__launch_bounds__(256)
__global__ void ms_kernel(const float* __restrict__ hPhi, const float* __restrict__ hBeta,
                          const float* __restrict__ Bms_n, const float* __restrict__ Bms_c,
                          const float* __restrict__ b_pmean, const float* __restrict__ b_pstd,
                          const float* __restrict__ b_bmean, const float* __restrict__ b_bstd,
                          const float* __restrict__ epsP, const float* __restrict__ epsB,
                          const float* __restrict__ phiPrior, const float* __restrict__ betaPrior,
                          float* __restrict__ phiS, float* __restrict__ betaS, float* __restrict__ acc)
{
    __shared__ float Hs[32][64];
    __shared__ float Wms[32][64];
    __shared__ float red[256];
    int bx = blockIdx.x;
    const float* H; const float* Bms; const float* bm; const float* bs;
    const float* eps; const float* prior; float* out;
    int m0, M, j0; bool isPhi;
    if (bx < 128) {
        m0 = (bx >> 2) * 64; j0 = (bx & 3) * 32; M = 2048; isPhi = true;
        H = hPhi; Bms = Bms_n; bm = b_pmean; bs = b_pstd; eps = epsP; prior = phiPrior; out = phiS;
    } else {
        m0 = 0; j0 = (bx - 128) * 32; M = 16; isPhi = false;
        H = hBeta; Bms = Bms_c; bm = b_bmean; bs = b_bstd; eps = epsB; prior = betaPrior; out = betaS;
    }
    int tid = threadIdx.x;
    int j  = tid & 31;
    int rr = tid >> 5;
    float accM[8] = {}, accS[8] = {};
    int srow = tid >> 3;
    int skq  = (tid & 7) * 4;
    for (int k0 = 0; k0 < 128; k0 += 32) {
        #pragma unroll
        for (int h2 = 0; h2 < 2; ++h2) {
            int row = srow + 32 * h2;
            int grow = m0 + row;
            float4 hv = make_float4(0.f,0.f,0.f,0.f);
            if (grow < M) hv = *(const float4*)(H + (size_t)grow*128 + k0 + skq);
            Hs[skq+0][row] = hv.x; Hs[skq+1][row] = hv.y; Hs[skq+2][row] = hv.z; Hs[skq+3][row] = hv.w;
        }
        {
            int rowIdx = srow + 32 * 0;   // two halves: mean rows 0..31, std 32..63
            #pragma unroll
            for (int h2 = 0; h2 < 2; ++h2) {
                int ri = rowIdx + 32 * h2;          // 0..63
                int grp = ri >> 5, jj2 = ri & 31;
                float4 wv = *(const float4*)(Bms + (size_t)(grp*128 + j0 + jj2)*128 + k0 + skq);
                Wms[skq+0][ri] = wv.x; Wms[skq+1][ri] = wv.y; Wms[skq+2][ri] = wv.z; Wms[skq+3][ri] = wv.w;
            }
        }
        __syncthreads();
        #pragma unroll
        for (int kk = 0; kk < 32; ++kk) {
            float hv[8];
            *(float4*)&hv[0] = *(const float4*)&Hs[kk][rr*8];
            *(float4*)&hv[4] = *(const float4*)&Hs[kk][rr*8+4];
            float wm = Wms[kk][j];
            float ws = Wms[kk][32 + j];
            #pragma unroll
            for (int i = 0; i < 8; ++i) {
                accM[i] = fmaf(hv[i], wm, accM[i]);
                accS[i] = fmaf(hv[i], ws, accS[i]);
            }
        }
        __syncthreads();
    }
    float bmv = bm[j0 + j], bsv = bs[j0 + j];
    float kld = 0.f;
    #pragma unroll
    for (int i = 0; i < 8; ++i) {
        int row = m0 + rr*8 + i;
        if (row < M) {
            size_t gi = (size_t)row * 128 + j0 + j;
            float mean = accM[i] + bmv;
            float stdv = softplusf_(accS[i] + bsv);
            out[gi] = mean + stdv * eps[gi];
            float d = mean - prior[gi];
            if (isPhi) kld += -logf_(stdv) + 0.5f*(stdv*stdv + d*d) - 0.5f;
            else       kld += (-2.3025850929940457f - logf_(stdv)) + 50.0f*(stdv*stdv + d*d) - 0.5f;
        }
    }
    red[tid] = kld; __syncthreads();
    for (int st = 128; st > 0; st >>= 1) { if (tid < st) red[tid] += red[tid + st]; __syncthreads(); }
    if (tid == 0) atomicAdd(acc + (isPhi ? 4 : 3), red[0]);
}

// ---------------------------------------------------------------------------
// Mt[n][k] = dot(beta_s[k,:], W_dec[n,:]) * LOG2E
// ---------------------------------------------------------------------------
__launch_bounds__(256)
__global__ void mt_kernel(const float* __restrict__ betaS, const float* __restrict__ W_dec, float* __restrict__ Mt)
{
    int tid = threadIdx.x, wid = tid >> 6, l = tid & 63;
    int n = blockIdx.x * 4 + wid;       // 512 blocks -> n < 2048
    int k = l & 15, q = l >> 4;
    const float* bs = betaS + k*128 + q*32;
    const float* wd = W_dec + (size_t)n*128 + q*32;
    float p = 0.f;
    #pragma unroll
    for (int jj = 0; jj < 32; ++jj) p = fmaf(bs[jj], wd[jj], p);
    p += __shfl_xor(p, 16);
    p += __shfl_xor(p, 32);
    if (l < 16) Mt[n*16 + l] = p * LOG2E;
}

// ---------------------------------------------------------------------------
// Fused z + nll. 512 thr, 64 edges/block, 256 blocks.
// Phase 1 (z): 8 waves x 8 edges -> Z into LDS (2 KB), kld_z.
// Phase 2 (nll): Mt register-resident (4 cols x 16 k), Z from LDS.
// ---------------------------------------------------------------------------
#define ZSTEP(A,B,Wv,Bv) { float4 a_=(A), b_=(B); \
    lp += a_.x*(Bv).x + a_.y*(Bv).y + a_.z*(Bv).z + a_.w*(Bv).w; \
    lq += (a_.x*b_.x)*(Wv).x + (a_.y*b_.y)*(Wv).y + (a_.z*b_.z)*(Wv).z + (a_.w*b_.w)*(Wv).w; }

__launch_bounds__(512, 2)
__global__ void znll_kernel(const float* __restrict__ phiS, const float* __restrict__ betaS,
                            const float* __restrict__ W_pi, const float* __restrict__ Mt,
                            const int* __restrict__ edges_t, const float* __restrict__ u_t,
                            float* __restrict__ acc)
{
    __shared__ float zbuf[64][16];
    __shared__ float ss[64][8], sc[64][8];
    __shared__ int   cbuf[64];
    __shared__ float kred[8];
    int tid = threadIdx.x, wid = tid >> 6, l = tid & 63;
    // ---- phase 1: gumbel-softmax z + kld_z ----
    {
        int k = l >> 2, q = l & 3;
        int d0 = q * 32;
        const float4* wp = (const float4*)(W_pi  + k*128 + d0);
        const float4* bp = (const float4*)(betaS + k*128 + d0);
        float4 wr0 = wp[0], wr1 = wp[1], wr2 = wp[2], wr3 = wp[3],
               wr4 = wp[4], wr5 = wp[5], wr6 = wp[6], wr7 = wp[7];
        float4 br0 = bp[0], br1 = bp[1], br2 = bp[2], br3 = bp[3],
               br4 = bp[4], br5 = bp[5], br6 = bp[6], br7 = bp[7];
        float kz = 0.f;
        #pragma unroll
        for (int it = 0; it < 8; ++it) {
            int jl = wid * 8 + it;               // 0..63
            int j = blockIdx.x * 64 + jl;        // 0..16383
            int e = j & 8191; int fl = j >> 13;
            int w = edges_t[e*2 + fl], c = edges_t[e*2 + (fl ^ 1)];
            const float4* pw4 = (const float4*)(phiS + (size_t)w*128 + d0);
            const float4* pc4 = (const float4*)(phiS + (size_t)c*128 + d0);
            float lq = 0.f, lp = 0.f;
            ZSTEP(pw4[0], pc4[0], wr0, br0); ZSTEP(pw4[1], pc4[1], wr1, br1);
            ZSTEP(pw4[2], pc4[2], wr2, br2); ZSTEP(pw4[3], pc4[3], wr3, br3);
            ZSTEP(pw4[4], pc4[4], wr4, br4); ZSTEP(pw4[5], pc4[5], wr5, br5);
            ZSTEP(pw4[6], pc4[6], wr6, br6); ZSTEP(pw4[7], pc4[7], wr7, br7);
            lq += __shfl_xor(lq, 1); lq += __shfl_xor(lq, 2);
            lp += __shfl_xor(lp, 1); lp += __shfl_xor(lp, 2);
            // posterior log-softmax (no max: |lq| bounded)
            float eq = expf_(lq);
            float sq = eq;
            sq += __shfl_xor(sq, 4); sq += __shfl_xor(sq, 8); sq += __shfl_xor(sq, 16); sq += __shfl_xor(sq, 32);
            float logpost = lq - logf_(sq);
            float post = eq * __builtin_amdgcn_rcpf(sq);
            // prior log-softmax (keep max)
            float mp = lp;
            mp = fmaxf(mp, __shfl_xor(mp, 4));  mp = fmaxf(mp, __shfl_xor(mp, 8));
            mp = fmaxf(mp, __shfl_xor(mp, 16)); mp = fmaxf(mp, __shfl_xor(mp, 32));
            float ep = expf_(lp - mp);
            float sp = ep;
            sp += __shfl_xor(sp, 4); sp += __shfl_xor(sp, 8); sp += __shfl_xor(sp, 16); sp += __shfl_xor(sp, 32);
            float logprior = (lp - mp) - logf_(sp);
            float v = post * (logpost - logprior);
            v += __shfl_xor(v, 4); v += __shfl_xor(v, 8); v += __shfl_xor(v, 16); v += __shfl_xor(v, 32);
            kz += v;
            // gumbel-softmax sample
            float u = u_t[(size_t)j*16 + k];
            float g = -logf_(-logf_(u + 1e-10f) + 1e-10f);
            float zl = lq + g;
            float ez = expf_(zl);
            float sz = ez;
            sz += __shfl_xor(sz, 4); sz += __shfl_xor(sz, 8); sz += __shfl_xor(sz, 16); sz += __shfl_xor(sz, 32);
            if (q == 0) zbuf[jl][k] = ez * __builtin_amdgcn_rcpf(sz);
            if (l == 0) cbuf[jl] = c;
        }
        if (l == 0) kred[wid] = kz;
    }
    __syncthreads();
    if (tid == 0) {
        float t = 0.f;
        #pragma unroll
        for (int w2 = 0; w2 < 8; ++w2) t += kred[w2];
        atomicAdd(acc + 1, t);
    }
    // ---- phase 2: nll ----
    int n0 = tid * 4;
    const float4* mp4 = (const float4*)(Mt + (size_t)n0 * 16);
    float4 M0 = mp4[0],  M1 = mp4[1],  M2 = mp4[2],  M3 = mp4[3];
    float4 M4 = mp4[4],  M5 = mp4[5],  M6 = mp4[6],  M7 = mp4[7];
    float4 M8 = mp4[8],  M9 = mp4[9],  M10 = mp4[10], M11 = mp4[11];
    float4 M12 = mp4[12], M13 = mp4[13], M14 = mp4[14], M15 = mp4[15];
    for (int e = 0; e < 64; ++e) {
        const float4* zp = (const float4*)&zbuf[e][0];
        float4 Z0 = zp[0], Z1 = zp[1], Z2 = zp[2], Z3 = zp[3];
        int c = cbuf[e];
        float v0 = D4(Z0, M0)  + D4(Z1, M1)  + D4(Z2, M2)  + D4(Z3, M3);
        float v1 = D4(Z0, M4)  + D4(Z1, M5)  + D4(Z2, M6)  + D4(Z3, M7);
        float v2 = D4(Z0, M8)  + D4(Z1, M9)  + D4(Z2, M10) + D4(Z3, M11);
        float v3 = D4(Z0, M12) + D4(Z1, M13) + D4(Z2, M14) + D4(Z3, M15);
        float s = exp2_(v0) + exp2_(v1) + exp2_(v2) + exp2_(v3);
        float cv = 0.f;
        cv = (c == n0    ) ? v0 : cv;
        cv = (c == n0 + 1) ? v1 : cv;
        cv = (c == n0 + 2) ? v2 : cv;
        cv = (c == n0 + 3) ? v3 : cv;
        #pragma unroll
        for (int m = 1; m < 64; m <<= 1) {
            s  += __shfl_xor(s, m);
            cv += __shfl_xor(cv, m);
        }
        if (l == 0) { ss[e][wid] = s; sc[e][wid] = cv; }
    }
    __syncthreads();
    if (tid < 64) {
        float S = 0.f, CV = 0.f;
        #pragma unroll
        for (int w2 = 0; w2 < 8; ++w2) { S += ss[tid][w2]; CV += sc[tid][w2]; }
        float val = LN2 * (log2_(S) - CV);
        #pragma unroll
        for (int m = 1; m < 64; m <<= 1) val += __shfl_xor(val, m);
        if (tid == 0) atomicAdd(acc + 0, val);
    }
}

__global__ void final_kernel(const float* __restrict__ acc, float* __restrict__ out)
{
    if (threadIdx.x == 0 && blockIdx.x == 0) {
        out[0] = acc[0] / CNT;
        out[1] = acc[1] / CNT;
        out[2] = 16.f * acc[2] / CNT;
        out[3] = acc[3] / CNT;
        out[4] = acc[4] / CNT;
    }
}

// ---------------------------------------------------------------------------
extern "C" void kernel_launch(void* const* d_in, const int* in_sizes, int n_in,
                              void* d_out, int out_size, void* d_ws, size_t ws_size,
                              hipStream_t stream)
{
    (void)in_sizes; (void)n_in; (void)out_size; (void)ws_size;
    const int*   edges   = (const int*)d_in[0];
    const int*   sidx    = (const int*)d_in[1];
    const float* eps_phi = (const float*)d_in[2];
    const float* eps_beta= (const float*)d_in[3];
    const float* u_g     = (const float*)d_in[4];
    const float* amE     = (const float*)d_in[5];
    const float* asE     = (const float*)d_in[6];
    const float* W_s2phi = (const float*)d_in[7];
    const float* b_s2phi = (const float*)d_in[8];
    const float* W_s2beta= (const float*)d_in[9];
    const float* b_s2beta= (const float*)d_in[10];
    const float* W_bmean = (const float*)d_in[11];
    const float* b_bmean = (const float*)d_in[12];
    const float* W_bstd  = (const float*)d_in[13];
    const float* b_bstd  = (const float*)d_in[14];
    const float* W_pmean = (const float*)d_in[15];
    const float* b_pmean = (const float*)d_in[16];
    const float* W_pstd  = (const float*)d_in[17];
    const float* b_pstd  = (const float*)d_in[18];
    const float* W_pi    = (const float*)d_in[19];
    const float* Wih_n   = (const float*)d_in[20];
    const float* Whh_n   = (const float*)d_in[21];
    const float* bih_n   = (const float*)d_in[22];
    const float* bhh_n   = (const float*)d_in[23];
    const float* Wih_c   = (const float*)d_in[24];
    const float* Whh_c   = (const float*)d_in[25];
    const float* bih_c   = (const float*)d_in[26];
    const float* bhh_c   = (const float*)d_in[27];
    const float* W_dec   = (const float*)d_in[28];

    float* ws     = (float*)d_ws;
    float* Bg_n   = ws;                    // 98304
    float* Bg_c   = Bg_n   + 98304;        // 98304
    float* Bms_n  = Bg_c   + 98304;        // 32768
    float* Bms_c  = Bms_n  + 32768;        // 32768
    float* a_m    = Bms_c  + 32768;        // 128
    float* phiA   = a_m    + 128;          // 262144
    float* phiB   = phiA   + 262144;       // 262144
    float* hphiA  = phiB   + 262144;       // 262144
    float* hphiB  = hphiA  + 262144;       // 262144
    float* betaA  = hphiB  + 262144;       // 2048
    float* betaB  = betaA  + 2048;         // 2048
    float* hbetaA = betaB  + 2048;         // 2048
    float* hbetaB = hbetaA + 2048;         // 2048
    float* Mt     = hbetaB + 2048;         // 32768
    float* acc    = Mt     + 32768;        // 8

    init_kernel<<<1025, 256, 0, stream>>>(Wih_n, Whh_n, Wih_c, Whh_c,
                                          W_pmean, W_pstd, W_bmean, W_bstd,
                                          Bg_n, Bg_c, Bms_n, Bms_c,
                                          hphiA, hbetaA, amE, asE, sidx, a_m, acc);
    phi0_kernel<<<66048, 256, 0, stream>>>(W_s2phi, b_s2phi, W_s2beta, b_s2beta, a_m, phiA, betaA);

    float* phiPrior = phiA;  float* phiS = phiB;
    float* betaPrior = betaA; float* betaS = betaB;
    float* hPhiOld = hphiA;  float* hPhiNew = hphiB;
    float* hBetaOld = hbetaA; float* hBetaNew = hbetaB;
    for (int t = 0; t < TT; ++t) {
        gru_kernel<<<132, 256, 0, stream>>>(phiPrior, betaPrior,
                                            hPhiOld, hPhiNew, hBetaOld, hBetaNew,
                                            Bg_n, Bg_c, bih_n, bhh_n, bih_c, bhh_c);
        ms_kernel<<<132, 256, 0, stream>>>(hPhiNew, hBetaNew, Bms_n, Bms_c,
                                           b_pmean, b_pstd, b_bmean, b_bstd,
                                           eps_phi + (size_t)t * 262144, eps_beta + (size_t)t * 2048,
                                           phiPrior, betaPrior, phiS, betaS, acc);
        mt_kernel<<<512, 256, 0, stream>>>(betaS, W_dec, Mt);
        znll_kernel<<<256, 512, 0, stream>>>(phiS, betaS, W_pi, Mt,
                                             edges + (size_t)t * EE * 2, u_g + (size_t)t * TWOE * KK, acc);
        float* tp = phiPrior; phiPrior = phiS; phiS = tp;
        float* tb = betaPrior; betaPrior = betaS; betaS = tb;
        float* th = hPhiOld; hPhiOld = hPhiNew; hPhiNew = th;
        float* tb2 = hBetaOld; hBetaOld = hBetaNew; hBetaNew = tb2;
    }
    final_kernel<<<1, 64, 0, stream>>>(acc, (float*)d_out);
}